// Round 5
// baseline (331.556 us; speedup 1.0000x reference)
//
#include <hip/hip_runtime.h>
#include <hip/hip_bf16.h>
#include <math.h>

#define B_ 32
#define T_ 2048
#define F_ 2048
#define H_ 1024
#define A_ 512

typedef __attribute__((ext_vector_type(8))) short short8;
typedef __attribute__((ext_vector_type(4))) float f32x4;

__device__ __forceinline__ unsigned short f2bf(float x) {
  union { float f; unsigned int u; } v; v.f = x;
  unsigned int r = v.u + 0x7FFFu + ((v.u >> 16) & 1u);
  return (unsigned short)(r >> 16);
}

#define GLOAD_LDS16(gp, lp) __builtin_amdgcn_global_load_lds( \
    (const __attribute__((address_space(1))) void*)(gp), \
    (__attribute__((address_space(3))) void*)(lp), 16, 0, 0)

#define SBAR   asm volatile("s_barrier" ::: "memory")
#define SCHEDB __builtin_amdgcn_sched_barrier(0)
#define WAIT_V2_L0 asm volatile("s_waitcnt vmcnt(2) lgkmcnt(0)" ::: "memory")

// ---------------- kernel 1: W_a f32 -> bf16 ----------------
__global__ __launch_bounds__(256) void k_convert_wa(const float* __restrict__ wa,
                                                    unsigned short* __restrict__ out) {
  int i = (blockIdx.x * 256 + threadIdx.x) * 4;
  float4 v = *(const float4*)(wa + i);
  ushort4 o;
  o.x = f2bf(v.x); o.y = f2bf(v.y); o.z = f2bf(v.z); o.w = f2bf(v.w);
  *(ushort4*)(out + i) = o;
}

// ---------------- kernel 2: hcomb[b][a] = hidden[b]·W_h[a] + b_h[a] + b_a[a] ----------------
__global__ __launch_bounds__(256) void k_hproj(const float* __restrict__ hidden,
                                               const float* __restrict__ Wh,
                                               const float* __restrict__ bh,
                                               const float* __restrict__ ba,
                                               float* __restrict__ hcomb) {
  int gw = (blockIdx.x * 256 + threadIdx.x) >> 6;   // wave id 0..16383
  int lane = threadIdx.x & 63;
  int b = gw >> 9, a = gw & 511;
  const float* wr = Wh + a * H_;
  const float* hr = hidden + b * H_;
  float acc = 0.f;
  #pragma unroll
  for (int k = 0; k < H_; k += 256) {
    float4 wv = *(const float4*)(wr + k + lane * 4);
    float4 hv = *(const float4*)(hr + k + lane * 4);
    acc += wv.x * hv.x + wv.y * hv.y + wv.z * hv.z + wv.w * hv.w;
  }
  #pragma unroll
  for (int off = 32; off; off >>= 1) acc += __shfl_xor(acc, off);
  if (lane == 0) hcomb[gw] = acc + bh[a] + ba[a];
}

// ---------------- kernel 3: fused energy GEMM ----------------
// energy[m] = (sum_a tanh(hcomb[b][a] + feat[m]·W_a[a]) * v_w[a] + v_b) / sqrt(512)
// M=65536, K=2048, N=512 full per block. BM=64, BK=64, 32 K-steps.
// FULL double-buffer (Bs 2x64KB + As 2x8KB = 144KB, 1 block/CU), ONE barrier
// per K-step, counted s_waitcnt vmcnt(2): A(t+2) reg-loads stay in flight
// ACROSS the barrier -> HBM queue never drains (the r1/r4 __syncthreads
// vmcnt(0) drain was the ~50% HBM duty-cycle loss).
__global__ __launch_bounds__(512, 2) void k_energy(
    const float* __restrict__ feat, const unsigned short* __restrict__ wab,
    const float* __restrict__ hcomb, const float* __restrict__ vw,
    const float* __restrict__ vb, float* __restrict__ energy) {
  // layout: Bs0 [0,64K) | Bs1 [64K,128K) | As0 [128K,+8K) | As1 [+8K,+16K)
  // e_red reuses [0,1K) after the K-loop (Bs0 dead by then).
  __shared__ __align__(16) char smem[147456];

  const int tid = threadIdx.x;
  const int lane = tid & 63;
  const int w = tid >> 6;
  const int wm = w >> 2, wn = w & 3;
  const int lrow = lane & 15;
  const int m0 = blockIdx.x * 64;
  const int bb = m0 >> 11;

  // ---- B staging: round r covers rows r*64 + (tid>>3); phys 16B-slot tid&7;
  // logical slot = phys ^ (row&7)  (XOR involution per 128B row)
  const int brow = tid >> 3;
  const unsigned short* const bsrc0 = wab + (size_t)brow * 2048 +
      (((((tid & 7) << 4) ^ ((brow & 7) << 4)) >> 1));

  // ---- A staging: row tid>>3 (64 rows), slot tid&7 (8 k-elems of 16B)
  const int arow = tid >> 3;
  const float* const asrc = feat + (size_t)(m0 + arow) * F_ + ((tid & 7) << 3);
  const int aw_byte = (arow << 7) + ((((tid & 7) << 4)) ^ ((arow & 7) << 4));

  // ---- fragment read offsets (bytes)
  const int xbase = ((lane >> 4) << 4) ^ ((lane & 7) << 4);
  const int a_row_byte = (wm * 32 + lrow) << 7;
  const int b_row_byte = (wn * 128 + lrow) << 7;

  f32x4 acc[2][8] = {};
  float4 avA0, avA1, avB0, avB1;   // slot0 holds A(even), slot1 holds A(odd)

#define STAGE_B(NXT, KB) do {                                                 \
    const unsigned short* bs_ = bsrc0 + (KB);                                 \
    char* bd_ = smem + (NXT) * 65536 + w * 1024;                              \
    _Pragma("unroll")                                                         \
    for (int r_ = 0; r_ < 8; ++r_)                                            \
      GLOAD_LDS16(bs_ + r_ * (64 * 2048), bd_ + r_ * 8192);                   \
  } while (0)

#define CVT_A(NXT, V0, V1) do {                                               \
    short8 apk_;                                                              \
    apk_[0] = (short)f2bf((V0).x); apk_[1] = (short)f2bf((V0).y);             \
    apk_[2] = (short)f2bf((V0).z); apk_[3] = (short)f2bf((V0).w);             \
    apk_[4] = (short)f2bf((V1).x); apk_[5] = (short)f2bf((V1).y);             \
    apk_[6] = (short)f2bf((V1).z); apk_[7] = (short)f2bf((V1).w);             \
    *(short8*)(smem + 131072 + (NXT) * 8192 + aw_byte) = apk_;                \
  } while (0)

#define COMPUTE_TILE(CURBUF) do {                                             \
    const char* As_ = smem + 131072 + (CURBUF) * 8192;                        \
    const char* Bs_ = smem + (CURBUF) * 65536;                                \
    _Pragma("unroll")                                                         \
    for (int kk = 0; kk < 2; ++kk) {                                          \
      const int xo = xbase ^ (kk << 6);                                       \
      const char* Ab = As_ + a_row_byte + xo;                                 \
      const char* Bb = Bs_ + b_row_byte + xo;                                 \
      short8 a0 = *(const short8*)(Ab);                                       \
      short8 a1 = *(const short8*)(Ab + 2048);                                \
      short8 b0 = *(const short8*)(Bb);                                       \
      short8 b1 = *(const short8*)(Bb + 2048);                                \
      short8 b2 = *(const short8*)(Bb + 4096);                                \
      short8 b3 = *(const short8*)(Bb + 6144);                                \
      acc[0][0] = __builtin_amdgcn_mfma_f32_16x16x32_bf16(a0, b0, acc[0][0], 0, 0, 0); \
      acc[1][0] = __builtin_amdgcn_mfma_f32_16x16x32_bf16(a1, b0, acc[1][0], 0, 0, 0); \
      acc[0][1] = __builtin_amdgcn_mfma_f32_16x16x32_bf16(a0, b1, acc[0][1], 0, 0, 0); \
      acc[1][1] = __builtin_amdgcn_mfma_f32_16x16x32_bf16(a1, b1, acc[1][1], 0, 0, 0); \
      acc[0][2] = __builtin_amdgcn_mfma_f32_16x16x32_bf16(a0, b2, acc[0][2], 0, 0, 0); \
      acc[1][2] = __builtin_amdgcn_mfma_f32_16x16x32_bf16(a1, b2, acc[1][2], 0, 0, 0); \
      acc[0][3] = __builtin_amdgcn_mfma_f32_16x16x32_bf16(a0, b3, acc[0][3], 0, 0, 0); \
      acc[1][3] = __builtin_amdgcn_mfma_f32_16x16x32_bf16(a1, b3, acc[1][3], 0, 0, 0); \
      short8 b4 = *(const short8*)(Bb + 8192);                                \
      short8 b5 = *(const short8*)(Bb + 10240);                               \
      short8 b6 = *(const short8*)(Bb + 12288);                               \
      short8 b7 = *(const short8*)(Bb + 14336);                               \
      acc[0][4] = __builtin_amdgcn_mfma_f32_16x16x32_bf16(a0, b4, acc[0][4], 0, 0, 0); \
      acc[1][4] = __builtin_amdgcn_mfma_f32_16x16x32_bf16(a1, b4, acc[1][4], 0, 0, 0); \
      acc[0][5] = __builtin_amdgcn_mfma_f32_16x16x32_bf16(a0, b5, acc[0][5], 0, 0, 0); \
      acc[1][5] = __builtin_amdgcn_mfma_f32_16x16x32_bf16(a1, b5, acc[1][5], 0, 0, 0); \
      acc[0][6] = __builtin_amdgcn_mfma_f32_16x16x32_bf16(a0, b6, acc[0][6], 0, 0, 0); \
      acc[1][6] = __builtin_amdgcn_mfma_f32_16x16x32_bf16(a1, b6, acc[1][6], 0, 0, 0); \
      acc[0][7] = __builtin_amdgcn_mfma_f32_16x16x32_bf16(a0, b7, acc[0][7], 0, 0, 0); \
      acc[1][7] = __builtin_amdgcn_mfma_f32_16x16x32_bf16(a1, b7, acc[1][7], 0, 0, 0); \
    }                                                                         \
  } while (0)

  // ---- prologue: A(0) first (oldest), B(0), A(1); cvt A(0) waits only A(0)
  {
    avA0 = *(const float4*)(asrc);
    avA1 = *(const float4*)(asrc + 4);
    STAGE_B(0, 0);
    SCHEDB;
    avB0 = *(const float4*)(asrc + 64);
    avB1 = *(const float4*)(asrc + 68);
    SCHEDB;
    CVT_A(0, avA0, avA1);   // compiler waits vmcnt(10): retires A(0) only
    SCHEDB;
    WAIT_V2_L0;             // retires B(0)x8; A(1) stays in flight
    SBAR;
  }

  // iter T: stage B(T+1)->Bs[NXT]; load A(T+2)->slot CUR; compute CUR;
  // cvt A(T+1) (slot NXT) -> As[NXT]; vmcnt(2) keeps A(T+2) in flight.
#define ITER(CUR, NXT, LD0, LD1, CV0, CV1, T) do {                            \
    STAGE_B(NXT, ((T) + 1) << 6);                                             \
    SCHEDB;                                                                   \
    LD0 = *(const float4*)(asrc + ((((T) + 2) & 31) << 6));                   \
    LD1 = *(const float4*)(asrc + ((((T) + 2) & 31) << 6) + 4);               \
    SCHEDB;                                                                   \
    COMPUTE_TILE(CUR);                                                        \
    CVT_A(NXT, CV0, CV1);                                                     \
    SCHEDB;                                                                   \
    WAIT_V2_L0;                                                               \
    SBAR;                                                                     \
  } while (0)

  #pragma unroll 1
  for (int tt = 0; tt < 15; ++tt) {
    const int t = tt * 2;
    ITER(0, 1, avA0, avA1, avB0, avB1, t);
    ITER(1, 0, avB0, avB1, avA0, avA1, t + 1);
  }
  ITER(0, 1, avA0, avA1, avB0, avB1, 30);
  COMPUTE_TILE(1);   // t=31
#undef ITER
#undef COMPUTE_TILE
#undef CVT_A
#undef STAGE_B

  // ---- epilogue: tanh, dot with v, reduce over N=512
  float hv[8], vv[8];
  #pragma unroll
  for (int ni = 0; ni < 8; ++ni) {
    int col = wn * 128 + ni * 16 + lrow;
    hv[ni] = hcomb[bb * 512 + col];
    vv[ni] = vw[col];
  }
  float (*e_red)[4] = (float(*)[4])(smem);   // Bs0 region, dead after t=30
  __syncthreads();
  const float vbv = vb[0];
  #pragma unroll
  for (int mi = 0; mi < 2; ++mi) {
    #pragma unroll
    for (int j = 0; j < 4; ++j) {
      float s = 0.f;
      #pragma unroll
      for (int ni = 0; ni < 8; ++ni) {
        float x = acc[mi][ni][j] + hv[ni];
        s += tanhf(x) * vv[ni];
      }
      s += __shfl_xor(s, 1); s += __shfl_xor(s, 2);
      s += __shfl_xor(s, 4); s += __shfl_xor(s, 8);
      if (lrow == 0) e_red[wm * 32 + mi * 16 + (lane >> 4) * 4 + j][wn] = s;
    }
  }
  __syncthreads();
  if (tid < 64) {
    float s = e_red[tid][0] + e_red[tid][1] + e_red[tid][2] + e_red[tid][3];
    energy[m0 + tid] = (s + vbv) * 0.04419417382415922f;  // 1/sqrt(512)
  }
}

// ---------------- kernel 4: softmax over T per batch ----------------
__global__ __launch_bounds__(256) void k_softmax(const float* __restrict__ energy,
                                                 float* __restrict__ alpha) {
  const int b = blockIdx.x, tid = threadIdx.x;
  const float* e = energy + b * T_;
  float4 v0 = ((const float4*)e)[tid * 2];
  float4 v1 = ((const float4*)e)[tid * 2 + 1];
  float m = fmaxf(fmaxf(fmaxf(v0.x, v0.y), fmaxf(v0.z, v0.w)),
                  fmaxf(fmaxf(v1.x, v1.y), fmaxf(v1.z, v1.w)));
  #pragma unroll
  for (int off = 32; off; off >>= 1) m = fmaxf(m, __shfl_xor(m, off));
  __shared__ float rmax[4], rsum[4];
  const int lane = tid & 63, wv = tid >> 6;
  if (!lane) rmax[wv] = m;
  __syncthreads();
  m = fmaxf(fmaxf(rmax[0], rmax[1]), fmaxf(rmax[2], rmax[3]));
  float x0 = expf(v0.x - m), x1 = expf(v0.y - m), x2 = expf(v0.z - m), x3 = expf(v0.w - m);
  float x4 = expf(v1.x - m), x5 = expf(v1.y - m), x6 = expf(v1.z - m), x7 = expf(v1.w - m);
  float s = ((x0 + x1) + (x2 + x3)) + ((x4 + x5) + (x6 + x7));
  #pragma unroll
  for (int off = 32; off; off >>= 1) s += __shfl_xor(s, off);
  if (!lane) rsum[wv] = s;
  __syncthreads();
  s = (rsum[0] + rsum[1]) + (rsum[2] + rsum[3]);
  float inv = 1.f / s;
  float4 o0 = {x0 * inv, x1 * inv, x2 * inv, x3 * inv};
  float4 o1 = {x4 * inv, x5 * inv, x6 * inv, x7 * inv};
  float* ao = alpha + b * T_;
  ((float4*)ao)[tid * 2] = o0;
  ((float4*)ao)[tid * 2 + 1] = o1;
}

// ---------------- kernel 5: context partials over t-chunks ----------------
__global__ __launch_bounds__(256) void k_ctx_partial(const float* __restrict__ feat,
                                                     const float* __restrict__ alpha,
                                                     float* __restrict__ part) {
  const int b = blockIdx.x, fh = blockIdx.y, tc = blockIdx.z;
  const int tid = threadIdx.x;
  __shared__ float sa[128];
  if (tid < 128) sa[tid] = alpha[b * T_ + tc * 128 + tid];
  __syncthreads();
  const int f = fh * 1024 + tid * 4;
  const float* fp = feat + ((size_t)(b * T_ + tc * 128)) * F_ + f;
  float4 s = {0.f, 0.f, 0.f, 0.f};
  #pragma unroll 4
  for (int t = 0; t < 128; ++t) {
    float a = sa[t];
    float4 v = *(const float4*)(fp + (size_t)t * F_);
    s.x += a * v.x; s.y += a * v.y; s.z += a * v.z; s.w += a * v.w;
  }
  *(float4*)(part + ((size_t)(b * 16 + tc)) * F_ + f) = s;
}

// ---------------- kernel 6: reduce partials ----------------
__global__ __launch_bounds__(256) void k_ctx_reduce(const float* __restrict__ part,
                                                    float* __restrict__ ctx) {
  const int i4 = blockIdx.x * 256 + threadIdx.x;  // float4 index, 16384 total
  const int b = i4 >> 9, f4 = i4 & 511;
  const float4* p = (const float4*)part;
  float4 s = {0.f, 0.f, 0.f, 0.f};
  #pragma unroll
  for (int tc = 0; tc < 16; ++tc) {
    float4 v = p[((b * 16 + tc) << 9) + f4];
    s.x += v.x; s.y += v.y; s.z += v.z; s.w += v.w;
  }
  ((float4*)ctx)[i4] = s;
}

extern "C" void kernel_launch(void* const* d_in, const int* in_sizes, int n_in,
                              void* d_out, int out_size, void* d_ws, size_t ws_size,
                              hipStream_t stream) {
  const float* feat   = (const float*)d_in[0];
  const float* hidden = (const float*)d_in[1];
  const float* Wh     = (const float*)d_in[2];
  const float* bh     = (const float*)d_in[3];
  const float* Wa     = (const float*)d_in[4];
  const float* ba     = (const float*)d_in[5];
  const float* vw     = (const float*)d_in[6];
  const float* vb     = (const float*)d_in[7];

  float* ctx   = (float*)d_out;            // [32][2048]
  float* alpha = (float*)d_out + B_ * T_;  // [32][2048]

  char* ws = (char*)d_ws;
  unsigned short* wab = (unsigned short*)ws;               // 2 MB bf16 W_a
  float* hcomb  = (float*)(ws + 2097152);                  // 64 KB
  float* energy = (float*)(ws + 2097152 + 65536);          // 256 KB
  float* part   = (float*)(ws + 2097152 + 65536 + 262144); // 4 MB

  k_convert_wa<<<dim3(1024), dim3(256), 0, stream>>>(Wa, wab);
  k_hproj<<<dim3(4096), dim3(256), 0, stream>>>(hidden, Wh, bh, ba, hcomb);
  k_energy<<<dim3(1024), dim3(512), 0, stream>>>(feat, wab, hcomb, vw, vb, energy);
  k_softmax<<<dim3(32), dim3(256), 0, stream>>>(energy, alpha);
  k_ctx_partial<<<dim3(32, 2, 16), dim3(256), 0, stream>>>(feat, alpha, part);
  k_ctx_reduce<<<dim3(64), dim3(256), 0, stream>>>(part, ctx);
}

// Round 6
// 318.654 us; speedup vs baseline: 1.0405x; 1.0405x over previous
//
#include <hip/hip_runtime.h>
#include <hip/hip_bf16.h>
#include <math.h>

#define B_ 32
#define T_ 2048
#define F_ 2048
#define H_ 1024
#define A_ 512

typedef __attribute__((ext_vector_type(8))) short short8;
typedef __attribute__((ext_vector_type(4))) float f32x4;

__device__ __forceinline__ unsigned short f2bf(float x) {
  union { float f; unsigned int u; } v; v.f = x;
  unsigned int r = v.u + 0x7FFFu + ((v.u >> 16) & 1u);
  return (unsigned short)(r >> 16);
}

__device__ __forceinline__ float bf2f(unsigned short u) {
  union { unsigned int u; float f; } v; v.u = ((unsigned int)u) << 16;
  return v.f;
}

#define GLOAD_LDS16(gp, lp) __builtin_amdgcn_global_load_lds( \
    (const __attribute__((address_space(1))) void*)(gp), \
    (__attribute__((address_space(3))) void*)(lp), 16, 0, 0)

// ---------------- kernel 1: W_a f32 -> bf16 ----------------
__global__ __launch_bounds__(256) void k_convert_wa(const float* __restrict__ wa,
                                                    unsigned short* __restrict__ out) {
  int i = (blockIdx.x * 256 + threadIdx.x) * 4;
  float4 v = *(const float4*)(wa + i);
  ushort4 o;
  o.x = f2bf(v.x); o.y = f2bf(v.y); o.z = f2bf(v.z); o.w = f2bf(v.w);
  *(ushort4*)(out + i) = o;
}

// ---------------- kernel 2: hcomb[b][a] = hidden[b]·W_h[a] + b_h[a] + b_a[a] ----------------
__global__ __launch_bounds__(256) void k_hproj(const float* __restrict__ hidden,
                                               const float* __restrict__ Wh,
                                               const float* __restrict__ bh,
                                               const float* __restrict__ ba,
                                               float* __restrict__ hcomb) {
  int gw = (blockIdx.x * 256 + threadIdx.x) >> 6;   // wave id 0..16383
  int lane = threadIdx.x & 63;
  int b = gw >> 9, a = gw & 511;
  const float* wr = Wh + a * H_;
  const float* hr = hidden + b * H_;
  float acc = 0.f;
  #pragma unroll
  for (int k = 0; k < H_; k += 256) {
    float4 w = *(const float4*)(wr + k + lane * 4);
    float4 h = *(const float4*)(hr + k + lane * 4);
    acc += w.x * h.x + w.y * h.y + w.z * h.z + w.w * h.w;
  }
  #pragma unroll
  for (int off = 32; off; off >>= 1) acc += __shfl_xor(acc, off);
  if (lane == 0) hcomb[gw] = acc + bh[a] + ba[a];
}

// ---------------- kernel 3: fused energy GEMM (round-1 structure, 295us) ----
// energy[m] = (sum_a tanh(hcomb[b][a] + feat[m]·W_a[a]) * v_w[a] + v_b) / sqrt(512)
// NEW vs r1: the bf16-converted A tile is ALSO stored to featb (side product,
// coalesced 16B/lane) so the context pass reads half the bytes.
__global__ __launch_bounds__(512, 4) void k_energy(
    const float* __restrict__ feat, const unsigned short* __restrict__ wab,
    const float* __restrict__ hcomb, const float* __restrict__ vw,
    const float* __restrict__ vb, float* __restrict__ energy,
    unsigned short* __restrict__ featb) {
  __shared__ __align__(16) unsigned short Bs[512 * 64];  // 64 KB
  __shared__ __align__(16) unsigned short As[64 * 64];   // 8 KB
  __shared__ float s_h[512];
  __shared__ float s_v[512];
  __shared__ float e_red[64][4];

  const int tid = threadIdx.x;
  const int lane = tid & 63;
  const int w = tid >> 6;
  const int wm = w >> 2, wn = w & 3;
  const int m0 = blockIdx.x * 64;
  const int bb = m0 >> 11;

  s_h[tid] = hcomb[bb * 512 + tid];
  s_v[tid] = vw[tid];

  f32x4 acc[2][8] = {};

  // ---- A staging geometry: thread -> (row = tid>>3, 8 k-elems at (tid&7)*8)
  const int arow = tid >> 3;
  unsigned short* const awp_base = As + arow * 64 +
      (((((tid & 7) * 16)) ^ ((arow & 7) << 4)) >> 1);
  const float* const aptr = feat + (size_t)(m0 + arow) * F_ + (tid & 7) * 8;
  unsigned short* const fbp = featb + (size_t)(m0 + arow) * F_ + ((tid & 7) << 3);

  // ---- B staging geometry (global_load_lds): round r writes LDS bytes
  // [r*8192 + tid*16); phys row n = r*64 + (tid>>3); logical k-bytes = rb ^ mask.
  const int bn = tid >> 3;
  const int blb = (((tid & 7) * 16) ^ ((bn & 7) << 4)) >> 1;  // k-elem offset
  const unsigned short* const bsrc = wab + bn * 2048 + blb;
  char* const ldsb = (char*)Bs + w * 1024;

  // ---- fragment read geometry
  const int lrow = lane & 15;
  const int xbase = ((lane >> 4) * 16) ^ ((lane & 7) << 4);  // swizzled k-byte, kk=0

  for (int ks = 0; ks < 32; ++ks) {
    const int k0 = ks * 64;
    __syncthreads();
    // B: 8 async rounds, 16 B/lane, linear LDS dest, pre-swizzled source
    const unsigned short* bs = bsrc + k0;
    #pragma unroll
    for (int r = 0; r < 8; ++r) {
      GLOAD_LDS16(bs + r * (64 * 2048), ldsb + r * 8192);
    }
    // A: load f32, convert RNE to bf16, swizzled ds_write_b128 + global side-store
    float4 av0 = *(const float4*)(aptr + k0);
    float4 av1 = *(const float4*)(aptr + k0 + 4);
    short8 apk;
    apk[0] = (short)f2bf(av0.x); apk[1] = (short)f2bf(av0.y);
    apk[2] = (short)f2bf(av0.z); apk[3] = (short)f2bf(av0.w);
    apk[4] = (short)f2bf(av1.x); apk[5] = (short)f2bf(av1.y);
    apk[6] = (short)f2bf(av1.z); apk[7] = (short)f2bf(av1.w);
    *(short8*)awp_base = apk;
    *(short8*)(fbp + k0) = apk;   // bf16 features side product (coalesced)
    __syncthreads();
    // compute: 2 K-slices of 32
    #pragma unroll
    for (int kk = 0; kk < 2; ++kk) {
      const int xo = (xbase ^ (kk << 6)) >> 1;
      const unsigned short* Ab = As + (wm * 32 + lrow) * 64 + xo;
      short8 a0 = *(const short8*)(Ab);
      short8 a1 = *(const short8*)(Ab + 16 * 64);
      const unsigned short* Bb = Bs + (wn * 128 + lrow) * 64 + xo;
      #pragma unroll
      for (int ni = 0; ni < 8; ++ni) {
        short8 bf = *(const short8*)(Bb + ni * 16 * 64);
        acc[0][ni] = __builtin_amdgcn_mfma_f32_16x16x32_bf16(a0, bf, acc[0][ni], 0, 0, 0);
        acc[1][ni] = __builtin_amdgcn_mfma_f32_16x16x32_bf16(a1, bf, acc[1][ni], 0, 0, 0);
      }
    }
  }

  // ---- epilogue: tanh, dot with v, reduce over N
  const float vbv = vb[0];
  #pragma unroll
  for (int mi = 0; mi < 2; ++mi) {
    #pragma unroll
    for (int j = 0; j < 4; ++j) {
      float s = 0.f;
      #pragma unroll
      for (int ni = 0; ni < 8; ++ni) {
        int col = wn * 128 + ni * 16 + lrow;
        float x = acc[mi][ni][j] + s_h[col];
        s += tanhf(x) * s_v[col];
      }
      s += __shfl_xor(s, 1); s += __shfl_xor(s, 2);
      s += __shfl_xor(s, 4); s += __shfl_xor(s, 8);
      if (lrow == 0) e_red[wm * 32 + mi * 16 + (lane >> 4) * 4 + j][wn] = s;
    }
  }
  __syncthreads();
  if (tid < 64) {
    float s = e_red[tid][0] + e_red[tid][1] + e_red[tid][2] + e_red[tid][3];
    energy[m0 + tid] = (s + vbv) * 0.04419417382415922f;  // 1/sqrt(512)
  }
}

// ---------------- kernel 4: softmax over T per batch ----------------
__global__ __launch_bounds__(256) void k_softmax(const float* __restrict__ energy,
                                                 float* __restrict__ alpha) {
  const int b = blockIdx.x, tid = threadIdx.x;
  const float* e = energy + b * T_;
  float4 v0 = ((const float4*)e)[tid * 2];
  float4 v1 = ((const float4*)e)[tid * 2 + 1];
  float m = fmaxf(fmaxf(fmaxf(v0.x, v0.y), fmaxf(v0.z, v0.w)),
                  fmaxf(fmaxf(v1.x, v1.y), fmaxf(v1.z, v1.w)));
  #pragma unroll
  for (int off = 32; off; off >>= 1) m = fmaxf(m, __shfl_xor(m, off));
  __shared__ float rmax[4], rsum[4];
  const int lane = tid & 63, wv = tid >> 6;
  if (!lane) rmax[wv] = m;
  __syncthreads();
  m = fmaxf(fmaxf(rmax[0], rmax[1]), fmaxf(rmax[2], rmax[3]));
  float x0 = expf(v0.x - m), x1 = expf(v0.y - m), x2 = expf(v0.z - m), x3 = expf(v0.w - m);
  float x4 = expf(v1.x - m), x5 = expf(v1.y - m), x6 = expf(v1.z - m), x7 = expf(v1.w - m);
  float s = ((x0 + x1) + (x2 + x3)) + ((x4 + x5) + (x6 + x7));
  #pragma unroll
  for (int off = 32; off; off >>= 1) s += __shfl_xor(s, off);
  if (!lane) rsum[wv] = s;
  __syncthreads();
  s = (rsum[0] + rsum[1]) + (rsum[2] + rsum[3]);
  float inv = 1.f / s;
  float4 o0 = {x0 * inv, x1 * inv, x2 * inv, x3 * inv};
  float4 o1 = {x4 * inv, x5 * inv, x6 * inv, x7 * inv};
  float* ao = alpha + b * T_;
  ((float4*)ao)[tid * 2] = o0;
  ((float4*)ao)[tid * 2 + 1] = o1;
}

// ---------------- kernel 5: context partials (bf16 features) ----------------
// part[b][tc][f] = sum_{t in chunk} alpha[t] * featb[b][t][f], 128 t per chunk.
__global__ __launch_bounds__(256) void k_ctx_partial(const unsigned short* __restrict__ featb,
                                                     const float* __restrict__ alpha,
                                                     float* __restrict__ part) {
  const int b = blockIdx.x, tc = blockIdx.y;
  const int tid = threadIdx.x;
  __shared__ float sa[128];
  if (tid < 128) sa[tid] = alpha[b * T_ + tc * 128 + tid];
  __syncthreads();
  const int col = tid * 8;
  const unsigned short* fp = featb + ((size_t)(b * T_ + tc * 128)) * F_ + col;
  float s0 = 0.f, s1 = 0.f, s2 = 0.f, s3 = 0.f;
  float s4 = 0.f, s5 = 0.f, s6 = 0.f, s7 = 0.f;
  #pragma unroll 4
  for (int t = 0; t < 128; ++t) {
    float a = sa[t];
    short8 v = *(const short8*)(fp + (size_t)t * F_);
    s0 += a * bf2f((unsigned short)v[0]);
    s1 += a * bf2f((unsigned short)v[1]);
    s2 += a * bf2f((unsigned short)v[2]);
    s3 += a * bf2f((unsigned short)v[3]);
    s4 += a * bf2f((unsigned short)v[4]);
    s5 += a * bf2f((unsigned short)v[5]);
    s6 += a * bf2f((unsigned short)v[6]);
    s7 += a * bf2f((unsigned short)v[7]);
  }
  float* pp = part + ((size_t)(b * 16 + tc)) * F_ + col;
  float4 o0 = {s0, s1, s2, s3};
  float4 o1 = {s4, s5, s6, s7};
  *(float4*)(pp) = o0;
  *(float4*)(pp + 4) = o1;
}

// ---------------- kernel 6: reduce partials ----------------
__global__ __launch_bounds__(256) void k_ctx_reduce(const float* __restrict__ part,
                                                    float* __restrict__ ctx) {
  const int i4 = blockIdx.x * 256 + threadIdx.x;  // float4 index, 16384 total
  const int b = i4 >> 9, f4 = i4 & 511;
  const float4* p = (const float4*)part;
  float4 s = {0.f, 0.f, 0.f, 0.f};
  #pragma unroll
  for (int tc = 0; tc < 16; ++tc) {
    float4 v = p[((b * 16 + tc) << 9) + f4];
    s.x += v.x; s.y += v.y; s.z += v.z; s.w += v.w;
  }
  ((float4*)ctx)[i4] = s;
}

extern "C" void kernel_launch(void* const* d_in, const int* in_sizes, int n_in,
                              void* d_out, int out_size, void* d_ws, size_t ws_size,
                              hipStream_t stream) {
  const float* feat   = (const float*)d_in[0];
  const float* hidden = (const float*)d_in[1];
  const float* Wh     = (const float*)d_in[2];
  const float* bh     = (const float*)d_in[3];
  const float* Wa     = (const float*)d_in[4];
  const float* ba     = (const float*)d_in[5];
  const float* vw     = (const float*)d_in[6];
  const float* vb     = (const float*)d_in[7];

  float* ctx   = (float*)d_out;            // [32][2048]
  float* alpha = (float*)d_out + B_ * T_;  // [32][2048]

  char* ws = (char*)d_ws;
  unsigned short* wab = (unsigned short*)ws;               // 2 MB bf16 W_a
  float* hcomb  = (float*)(ws + 2097152);                  // 64 KB
  float* energy = (float*)(ws + 2097152 + 65536);          // 256 KB
  float* part   = (float*)(ws + 4194304);                  // 4 MB
  unsigned short* featb = (unsigned short*)(ws + 16777216); // 256 MB bf16 features

  k_convert_wa<<<dim3(1024), dim3(256), 0, stream>>>(Wa, wab);
  k_hproj<<<dim3(4096), dim3(256), 0, stream>>>(hidden, Wh, bh, ba, hcomb);
  k_energy<<<dim3(1024), dim3(512), 0, stream>>>(feat, wab, hcomb, vw, vb, energy, featb);
  k_softmax<<<dim3(32), dim3(256), 0, stream>>>(energy, alpha);
  k_ctx_partial<<<dim3(32, 16), dim3(256), 0, stream>>>(featb, alpha, part);
  k_ctx_reduce<<<dim3(64), dim3(256), 0, stream>>>(part, ctx);
}